// Round 8
// baseline (833.667 us; speedup 1.0000x reference)
//
#include <hip/hip_runtime.h>
#include <math.h>

#define B 32
#define S 2048
#define S1 2049
#define D 128
#define H 16
#define DT 2048   // D*H
#define EPS 1e-5f
#define SCALE 0.08838834764831845f  // 1/sqrt(128)

typedef float f4v __attribute__((ext_vector_type(4)));

// DPP rotate-and-add within 16-lane rows: after ror 1,2,4,8 every lane holds
// the sum of its 16-lane row.  Pure VALU -- no DS-pipe traffic.
__device__ __forceinline__ float dpp_row_sum16(float x) {
    int xi;
    xi = __builtin_amdgcn_update_dpp(0, __float_as_int(x), 0x121, 0xf, 0xf, false);
    x += __int_as_float(xi);   // + ror1
    xi = __builtin_amdgcn_update_dpp(0, __float_as_int(x), 0x122, 0xf, 0xf, false);
    x += __int_as_float(xi);   // + ror2
    xi = __builtin_amdgcn_update_dpp(0, __float_as_int(x), 0x124, 0xf, 0xf, false);
    x += __int_as_float(xi);   // + ror4
    xi = __builtin_amdgcn_update_dpp(0, __float_as_int(x), 0x128, 0xf, 0xf, false);
    x += __int_as_float(xi);   // + ror8
    return x;
}

// ---------------------------------------------------------------------------
// Kernel 0: zero the per-batch completion counters (graph-safe reset).
// ---------------------------------------------------------------------------
__global__ void reset_kernel(unsigned* __restrict__ c) {
    if (threadIdx.x < B) c[threadIdx.x] = 0u;
}

// ---------------------------------------------------------------------------
// Kernel 1: fully fused decode step.
// Grid: B*H = 512 blocks of 1024 threads = 32 half-waves.
// Prologue: per-head QKV projection + cache append of k_new/v_new.
// K-pass:  NT-load K -> store to cache -> per-lane dot -> DPP row-sum ->
//          two 16-lane partials to LDS (no cross-lane DS ops).
// softmax: fold partials, block max/sum over 2049 scores.
// V-pass:  NT-load V -> store to cache -> acc += p * v.
// Tail:    block combine -> ys to workspace; last block per batch (atomic
//          counter) runs out-proj + bias + residual + LayerNorm.
// ---------------------------------------------------------------------------
__global__ void __launch_bounds__(1024)
attn_kernel(const float* __restrict__ x,
            const float* __restrict__ Wqkv,
            const float* __restrict__ bqkv,
            const float* __restrict__ past_k,
            const float* __restrict__ past_v,
            const float* __restrict__ Wout,
            const float* __restrict__ bout,
            float* __restrict__ out_k,
            float* __restrict__ out_v,
            float* __restrict__ ys_g,
            unsigned* __restrict__ counters,
            float* __restrict__ out) {
    const int bh = blockIdx.x;
    const int b = bh >> 4;
    const int h = bh & (H - 1);
    const int tid  = threadIdx.x;
    const int wave = tid >> 6;       // 0..15
    const int lane = tid & 63;
    const int l32  = tid & 31;
    const int rg   = tid >> 5;       // half-wave 0..31

    __shared__ float xs[D];
    __shared__ float qkvs[3 * D];    // q | k_new | v_new
    __shared__ float scp[2 * S];     // 16 KB: two 16-lane partials per row
    __shared__ float swm[16];
    __shared__ float swl[16];
    __shared__ float sacc[32 * D];   // 16 KB
    __shared__ float sh_snew;
    __shared__ float sh_enew;
    __shared__ unsigned sh_last;
    // winner-only (out-proj) buffers
    __shared__ float ys[DT];         // 8 KB
    __shared__ float pp[D * 8];      // 4 KB
    __shared__ float tb[D];

    const f4v* __restrict__ kin  = (const f4v*)past_k + (size_t)bh * S * 32;
    const f4v* __restrict__ vin  = (const f4v*)past_v + (size_t)bh * S * 32;
    f4v* __restrict__ kout = (f4v*)out_k + (size_t)bh * S1 * 32;
    f4v* __restrict__ vout = (f4v*)out_v + (size_t)bh * S1 * 32;

    // ---- prologue: per-head QKV projection ----
    if (tid < D) xs[tid] = x[b * D + tid];
    __syncthreads();
    if (tid < 3 * D) {
        const int which = tid >> 7;          // 0=q, 1=k_new, 2=v_new
        const int d = tid & 127;
        const int row = which * DT + h * D + d;
        const float* w = Wqkv + (size_t)row * D;
        float acc = bqkv[row];
#pragma unroll
        for (int j = 0; j < D; j += 4) {
            float4 w4 = *reinterpret_cast<const float4*>(w + j);
            acc = fmaf(w4.x, xs[j + 0], acc);
            acc = fmaf(w4.y, xs[j + 1], acc);
            acc = fmaf(w4.z, xs[j + 2], acc);
            acc = fmaf(w4.w, xs[j + 3], acc);
        }
        qkvs[tid] = acc;
        if (which == 1) ((float*)kout)[(size_t)S * D + d] = acc;
        if (which == 2) ((float*)vout)[(size_t)S * D + d] = acc;
    }
    __syncthreads();

    // new-token score (wave 0, from LDS)
    if (tid < 64) {
        float pd = qkvs[2 * tid] * qkvs[D + 2 * tid]
                 + qkvs[2 * tid + 1] * qkvs[D + 2 * tid + 1];
        pd += __shfl_xor(pd, 1);
        pd += __shfl_xor(pd, 2);
        pd += __shfl_xor(pd, 4);
        pd += __shfl_xor(pd, 8);
        pd += __shfl_xor(pd, 16);
        pd += __shfl_xor(pd, 32);
        if (tid == 0) sh_snew = pd * SCALE;
    }

    const f4v q4 = ((const f4v*)qkvs)[l32];

    // ---- K-pass: copy + scores (DPP reduce, no DS cross-lane) ----
#pragma unroll 8
    for (int it = 0; it < S / 32; ++it) {
        const int r = it * 32 + rg;
        const size_t off = (size_t)r * 32 + l32;
        f4v k4 = __builtin_nontemporal_load(&kin[off]);
        kout[off] = k4;
        f4v t = k4 * q4;
        float p = t.x + t.y + t.z + t.w;
        p = dpp_row_sum16(p);
        if ((l32 & 15) == 0) scp[(l32 >> 4) * S + r] = p * SCALE;
    }
    __syncthreads();

    // ---- block softmax over 2048 past rows + new token ----
    const float s0v = scp[tid] + scp[S + tid];
    const float s1v = scp[tid + 1024] + scp[S + tid + 1024];
    const float sxv = (tid == 0) ? sh_snew : -1e30f;
    float m = fmaxf(fmaxf(s0v, s1v), sxv);
#pragma unroll
    for (int off = 1; off < 64; off <<= 1) m = fmaxf(m, __shfl_xor(m, off));
    if (lane == 0) swm[wave] = m;
    __syncthreads();
    float M = swm[0];
#pragma unroll
    for (int g = 1; g < 16; ++g) M = fmaxf(M, swm[g]);
    const float e0 = __expf(s0v - M);
    const float e1 = __expf(s1v - M);
    scp[tid] = e0;
    scp[tid + 1024] = e1;
    float lsum = e0 + e1;
    if (tid == 0) {
        sh_enew = __expf(sh_snew - M);
        lsum += sh_enew;
    }
#pragma unroll
    for (int off = 1; off < 64; off <<= 1) lsum += __shfl_xor(lsum, off);
    if (lane == 0) swl[wave] = lsum;
    __syncthreads();
    float L = swl[0];
#pragma unroll
    for (int g = 1; g < 16; ++g) L += swl[g];
    const float invL = 1.0f / L;

    // ---- V-pass: copy + weighted accumulate ----
    f4v acc = (f4v){0.f, 0.f, 0.f, 0.f};
#pragma unroll 8
    for (int it = 0; it < S / 32; ++it) {
        const int r = it * 32 + rg;
        const size_t off = (size_t)r * 32 + l32;
        f4v v4 = __builtin_nontemporal_load(&vin[off]);
        vout[off] = v4;
        acc += v4 * scp[r];
    }

    // ---- combine 32 rowgroups + new token, normalize, publish ----
    ((f4v*)sacc)[rg * 32 + l32] = acc;
    __syncthreads();

    if (tid < D) {
        float y = 0.f;
#pragma unroll
        for (int g = 0; g < 32; ++g) y += sacc[g * D + tid];
        y = fmaf(sh_enew, qkvs[2 * D + tid], y);
        ys_g[(size_t)bh * D + tid] = y * invL;
    }
    __threadfence();
    __syncthreads();
    if (tid == 0)
        sh_last = (atomicAdd(&counters[b], 1u) == H - 1) ? 1u : 0u;
    __syncthreads();
    if (!sh_last) return;

    // ---- winner: out-proj + bias + residual + LayerNorm for batch b ----
    __threadfence();
    ys[tid]        = ys_g[(size_t)b * DT + tid];
    ys[tid + 1024] = ys_g[(size_t)b * DT + tid + 1024];
    __syncthreads();

    {
        const int d = tid >> 3;
        const int sub = tid & 7;
        const float* w = Wout + (size_t)d * DT + sub * 256;
        const float* y = ys + sub * 256;
        float a = 0.f;
#pragma unroll
        for (int j = 0; j < 256; j += 4) {
            float4 w4 = *reinterpret_cast<const float4*>(w + j);
            a = fmaf(w4.x, y[j + 0], a);
            a = fmaf(w4.y, y[j + 1], a);
            a = fmaf(w4.z, y[j + 2], a);
            a = fmaf(w4.w, y[j + 3], a);
        }
        pp[d * 8 + sub] = a;
    }
    __syncthreads();

    float val = 0.f;
    if (tid < D) {
        float a = 0.f;
#pragma unroll
        for (int g = 0; g < 8; ++g) a += pp[tid * 8 + g];
        val = a + bout[tid] + xs[tid];
        tb[tid] = val;
    }
    __syncthreads();
    for (int off = 64; off > 0; off >>= 1) {
        if (tid < off) tb[tid] += tb[tid + off];
        __syncthreads();
    }
    const float mu = tb[0] * (1.0f / D);
    __syncthreads();
    const float diff = val - mu;
    if (tid < D) tb[tid] = diff * diff;
    __syncthreads();
    for (int off = 64; off > 0; off >>= 1) {
        if (tid < off) tb[tid] += tb[tid + off];
        __syncthreads();
    }
    const float var = tb[0] * (1.0f / D);
    if (tid < D) out[(size_t)b * D + tid] = diff / sqrtf(var + EPS);
}

// ---------------------------------------------------------------------------
extern "C" void kernel_launch(void* const* d_in, const int* in_sizes, int n_in,
                              void* d_out, int out_size, void* d_ws, size_t ws_size,
                              hipStream_t stream) {
    const float* x      = (const float*)d_in[0];
    const float* past_k = (const float*)d_in[1];
    const float* past_v = (const float*)d_in[2];
    const float* Wqkv   = (const float*)d_in[3];
    const float* bqkv   = (const float*)d_in[4];
    const float* Wout   = (const float*)d_in[5];
    const float* bout   = (const float*)d_in[6];

    float* out   = (float*)d_out;                       // (B,1,D)
    float* out_k = out + (size_t)B * D;                 // (B,H,S1,D)
    float* out_v = out_k + (size_t)B * H * S1 * D;      // (B,H,S1,D)

    float*    ys_g     = (float*)d_ws;                  // B*DT floats
    unsigned* counters = (unsigned*)(ys_g + (size_t)B * DT);  // B uints

    reset_kernel<<<1, 64, 0, stream>>>(counters);
    attn_kernel<<<B * H, 1024, 0, stream>>>(
        x, Wqkv, bqkv, past_k, past_v, Wout, bout,
        out_k, out_v, ys_g, counters, out);
}

// Round 9
// 461.708 us; speedup vs baseline: 1.8056x; 1.8056x over previous
//
#include <hip/hip_runtime.h>
#include <math.h>

#define B 32
#define S 2048
#define S1 2049
#define D 128
#define H 16
#define DT 2048   // D*H
#define EPS 1e-5f
#define SCALE 0.08838834764831845f  // 1/sqrt(128)

typedef float f4v __attribute__((ext_vector_type(4)));

// ---------------------------------------------------------------------------
// Kernel 1: fused per-head QKV projection + cache-append + cache-copy +
// full single-(b,h) attention, phase-split.  (R7 structure, unroll 16.)
// Grid: B*H = 512 blocks of 1024 threads = 32 half-waves.
// ---------------------------------------------------------------------------
__global__ void __launch_bounds__(1024)
attn_kernel(const float* __restrict__ x,
            const float* __restrict__ Wqkv,
            const float* __restrict__ bqkv,
            const float* __restrict__ past_k,
            const float* __restrict__ past_v,
            float* __restrict__ out_k,
            float* __restrict__ out_v,
            float* __restrict__ ys_g) {
    const int bh = blockIdx.x;
    const int b = bh >> 4;
    const int h = bh & (H - 1);
    const int tid  = threadIdx.x;
    const int wave = tid >> 6;       // 0..15
    const int lane = tid & 63;
    const int l32  = tid & 31;
    const int rg   = tid >> 5;       // half-wave 0..31

    __shared__ float xs[D];
    __shared__ float qkvs[3 * D];    // q | k_new | v_new for this head
    __shared__ float sc[S1 + 3];     // 2049 scores
    __shared__ float swm[16];
    __shared__ float swl[16];
    __shared__ float sacc[32 * D];   // 16 KB

    const f4v* __restrict__ kin  = (const f4v*)past_k + (size_t)bh * S * 32;
    const f4v* __restrict__ vin  = (const f4v*)past_v + (size_t)bh * S * 32;
    f4v* __restrict__ kout = (f4v*)out_k + (size_t)bh * S1 * 32;
    f4v* __restrict__ vout = (f4v*)out_v + (size_t)bh * S1 * 32;

    // ---- prologue: per-head QKV projection ----
    if (tid < D) xs[tid] = x[b * D + tid];
    __syncthreads();
    if (tid < 3 * D) {
        const int which = tid >> 7;          // 0=q, 1=k_new, 2=v_new
        const int d = tid & 127;
        const int row = which * DT + h * D + d;
        const float* w = Wqkv + (size_t)row * D;
        float acc = bqkv[row];
#pragma unroll
        for (int j = 0; j < D; j += 4) {
            float4 w4 = *reinterpret_cast<const float4*>(w + j);
            acc = fmaf(w4.x, xs[j + 0], acc);
            acc = fmaf(w4.y, xs[j + 1], acc);
            acc = fmaf(w4.z, xs[j + 2], acc);
            acc = fmaf(w4.w, xs[j + 3], acc);
        }
        qkvs[tid] = acc;
        if (which == 1) ((float*)kout)[(size_t)S * D + d] = acc;
        if (which == 2) ((float*)vout)[(size_t)S * D + d] = acc;
    }
    __syncthreads();

    const f4v q4 = ((const f4v*)qkvs)[l32];

    // ---- K-pass: copy + scores (no loop-carried dependencies) ----
#pragma unroll 16
    for (int it = 0; it < S / 32; ++it) {
        const int r = it * 32 + rg;
        const size_t off = (size_t)r * 32 + l32;
        f4v k4 = __builtin_nontemporal_load(&kin[off]);
        kout[off] = k4;
        f4v t = k4 * q4;
        float p = t.x + t.y + t.z + t.w;
        p += __shfl_xor(p, 1);
        p += __shfl_xor(p, 2);
        p += __shfl_xor(p, 4);
        p += __shfl_xor(p, 8);
        p += __shfl_xor(p, 16);
        if (l32 == 0) sc[r] = p * SCALE;
    }
    // new-token score by wave 0 (from LDS q/k_new)
    if (tid < 64) {
        float pd = qkvs[2 * tid] * qkvs[D + 2 * tid]
                 + qkvs[2 * tid + 1] * qkvs[D + 2 * tid + 1];
        pd += __shfl_xor(pd, 1);
        pd += __shfl_xor(pd, 2);
        pd += __shfl_xor(pd, 4);
        pd += __shfl_xor(pd, 8);
        pd += __shfl_xor(pd, 16);
        pd += __shfl_xor(pd, 32);
        if (tid == 0) sc[S] = pd * SCALE;
    }
    __syncthreads();

    // ---- block softmax over sc[0..2048] ----
    const float s0v = sc[tid];
    const float s1v = sc[tid + 1024];
    const float sxv = (tid == 0) ? sc[S] : -1e30f;
    float m = fmaxf(fmaxf(s0v, s1v), sxv);
#pragma unroll
    for (int off = 1; off < 64; off <<= 1) m = fmaxf(m, __shfl_xor(m, off));
    if (lane == 0) swm[wave] = m;
    __syncthreads();
    float M = swm[0];
#pragma unroll
    for (int g = 1; g < 16; ++g) M = fmaxf(M, swm[g]);
    const float e0 = __expf(s0v - M);
    const float e1 = __expf(s1v - M);
    sc[tid] = e0;
    sc[tid + 1024] = e1;
    float lsum = e0 + e1;
    if (tid == 0) {
        const float e2 = __expf(sxv - M);
        sc[S] = e2;
        lsum += e2;
    }
#pragma unroll
    for (int off = 1; off < 64; off <<= 1) lsum += __shfl_xor(lsum, off);
    if (lane == 0) swl[wave] = lsum;
    __syncthreads();
    float L = swl[0];
#pragma unroll
    for (int g = 1; g < 16; ++g) L += swl[g];
    const float invL = 1.0f / L;

    // ---- V-pass: copy + weighted accumulate (1 carried FMA) ----
    f4v acc = (f4v){0.f, 0.f, 0.f, 0.f};
#pragma unroll 16
    for (int it = 0; it < S / 32; ++it) {
        const int r = it * 32 + rg;
        const size_t off = (size_t)r * 32 + l32;
        f4v v4 = __builtin_nontemporal_load(&vin[off]);
        vout[off] = v4;
        acc += v4 * sc[r];
    }

    // ---- combine 32 rowgroups + new token, normalize, write ----
    ((f4v*)sacc)[rg * 32 + l32] = acc;
    __syncthreads();

    if (tid < D) {
        float y = 0.f;
#pragma unroll
        for (int g = 0; g < 32; ++g) y += sacc[g * D + tid];
        y = fmaf(sc[S], qkvs[2 * D + tid], y);
        ys_g[(size_t)bh * D + tid] = y * invL;
    }
}

// ---------------------------------------------------------------------------
// Kernel 2: out-proj + bias + residual + LayerNorm.  One block per b,
// 1024 threads.  GEMV: thread t -> d = t>>3, j-chunk sub = t&7.
// ---------------------------------------------------------------------------
__global__ void __launch_bounds__(1024)
out_proj_kernel(const float* __restrict__ x,
                const float* __restrict__ ys_g,
                const float* __restrict__ Wout,
                const float* __restrict__ bout,
                float* __restrict__ out) {
    const int b = blockIdx.x;
    const int t = threadIdx.x;
    __shared__ float ys[DT];        // 8 KB
    __shared__ float pp[D * 8];     // 4 KB
    __shared__ float tb[D];

    ys[t]        = ys_g[(size_t)b * DT + t];
    ys[t + 1024] = ys_g[(size_t)b * DT + t + 1024];
    __syncthreads();

    {
        const int d = t >> 3;
        const int sub = t & 7;
        const float* w = Wout + (size_t)d * DT + sub * 256;
        const float* y = ys + sub * 256;
        float acc = 0.f;
#pragma unroll
        for (int j = 0; j < 256; j += 4) {
            float4 w4 = *reinterpret_cast<const float4*>(w + j);
            acc = fmaf(w4.x, y[j + 0], acc);
            acc = fmaf(w4.y, y[j + 1], acc);
            acc = fmaf(w4.z, y[j + 2], acc);
            acc = fmaf(w4.w, y[j + 3], acc);
        }
        pp[d * 8 + sub] = acc;
    }
    __syncthreads();

    float val = 0.f;
    if (t < D) {
        float a = 0.f;
#pragma unroll
        for (int g = 0; g < 8; ++g) a += pp[t * 8 + g];
        val = a + bout[t] + x[b * D + t];
        tb[t] = val;
    }
    __syncthreads();
    for (int off = 64; off > 0; off >>= 1) {
        if (t < off) tb[t] += tb[t + off];
        __syncthreads();
    }
    const float mu = tb[0] * (1.0f / D);
    __syncthreads();
    const float diff = val - mu;
    if (t < D) tb[t] = diff * diff;
    __syncthreads();
    for (int off = 64; off > 0; off >>= 1) {
        if (t < off) tb[t] += tb[t + off];
        __syncthreads();
    }
    const float var = tb[0] * (1.0f / D);
    if (t < D) out[(size_t)b * D + t] = diff / sqrtf(var + EPS);
}

// ---------------------------------------------------------------------------
extern "C" void kernel_launch(void* const* d_in, const int* in_sizes, int n_in,
                              void* d_out, int out_size, void* d_ws, size_t ws_size,
                              hipStream_t stream) {
    const float* x      = (const float*)d_in[0];
    const float* past_k = (const float*)d_in[1];
    const float* past_v = (const float*)d_in[2];
    const float* Wqkv   = (const float*)d_in[3];
    const float* bqkv   = (const float*)d_in[4];
    const float* Wout   = (const float*)d_in[5];
    const float* bout   = (const float*)d_in[6];

    float* out   = (float*)d_out;                       // (B,1,D)
    float* out_k = out + (size_t)B * D;                 // (B,H,S1,D)
    float* out_v = out_k + (size_t)B * H * S1 * D;      // (B,H,S1,D)

    float* ys_g = (float*)d_ws;                         // B*DT

    attn_kernel<<<B * H, 1024, 0, stream>>>(
        x, Wqkv, bqkv, past_k, past_v, out_k, out_v, ys_g);
    out_proj_kernel<<<B, 1024, 0, stream>>>(
        x, ys_g, Wout, bout, out);
}

// Round 10
// 441.721 us; speedup vs baseline: 1.8873x; 1.0452x over previous
//
#include <hip/hip_runtime.h>
#include <math.h>

#define B 32
#define S 2048
#define S1 2049
#define D 128
#define H 16
#define DT 2048   // D*H
#define EPS 1e-5f
#define SCALE 0.08838834764831845f  // 1/sqrt(128)

typedef float f4v __attribute__((ext_vector_type(4)));

// ---------------------------------------------------------------------------
// Kernel 1: fused per-head QKV projection + cache-append + cache-copy +
// full single-(b,h) attention, phase-split.  (R7 structure — best: 441 us.)
// Grid: B*H = 512 blocks of 1024 threads = 32 half-waves.
// Prologue: block computes its own q/k_new/v_new (Wqkv slices L2/L3-resident),
//           writes k_new/v_new to cache row 2048.
// K-pass:  NT-load K -> regular store to cache -> dot -> score to LDS.
// softmax: block reduction over 2049 scores.
// V-pass:  NT-load V -> regular store to cache -> acc += p * v.
// unroll 8: measured optimum (16 regressed +21 us, R9).
// ---------------------------------------------------------------------------
__global__ void __launch_bounds__(1024)
attn_kernel(const float* __restrict__ x,
            const float* __restrict__ Wqkv,
            const float* __restrict__ bqkv,
            const float* __restrict__ past_k,
            const float* __restrict__ past_v,
            float* __restrict__ out_k,
            float* __restrict__ out_v,
            float* __restrict__ ys_g) {
    const int bh = blockIdx.x;
    const int b = bh >> 4;
    const int h = bh & (H - 1);
    const int tid  = threadIdx.x;
    const int wave = tid >> 6;       // 0..15
    const int lane = tid & 63;
    const int l32  = tid & 31;
    const int rg   = tid >> 5;       // half-wave 0..31

    __shared__ float xs[D];
    __shared__ float qkvs[3 * D];    // q | k_new | v_new for this head
    __shared__ float sc[S1 + 3];     // 2049 scores
    __shared__ float swm[16];
    __shared__ float swl[16];
    __shared__ float sacc[32 * D];   // 16 KB

    const f4v* __restrict__ kin  = (const f4v*)past_k + (size_t)bh * S * 32;
    const f4v* __restrict__ vin  = (const f4v*)past_v + (size_t)bh * S * 32;
    f4v* __restrict__ kout = (f4v*)out_k + (size_t)bh * S1 * 32;
    f4v* __restrict__ vout = (f4v*)out_v + (size_t)bh * S1 * 32;

    // ---- prologue: per-head QKV projection ----
    if (tid < D) xs[tid] = x[b * D + tid];
    __syncthreads();
    if (tid < 3 * D) {
        const int which = tid >> 7;          // 0=q, 1=k_new, 2=v_new
        const int d = tid & 127;
        const int row = which * DT + h * D + d;
        const float* w = Wqkv + (size_t)row * D;
        float acc = bqkv[row];
#pragma unroll
        for (int j = 0; j < D; j += 4) {
            float4 w4 = *reinterpret_cast<const float4*>(w + j);
            acc = fmaf(w4.x, xs[j + 0], acc);
            acc = fmaf(w4.y, xs[j + 1], acc);
            acc = fmaf(w4.z, xs[j + 2], acc);
            acc = fmaf(w4.w, xs[j + 3], acc);
        }
        qkvs[tid] = acc;
        if (which == 1) ((float*)kout)[(size_t)S * D + d] = acc;
        if (which == 2) ((float*)vout)[(size_t)S * D + d] = acc;
    }
    __syncthreads();

    const f4v q4 = ((const f4v*)qkvs)[l32];

    // ---- K-pass: copy + scores (no loop-carried dependencies) ----
#pragma unroll 8
    for (int it = 0; it < S / 32; ++it) {
        const int r = it * 32 + rg;
        const size_t off = (size_t)r * 32 + l32;
        f4v k4 = __builtin_nontemporal_load(&kin[off]);
        kout[off] = k4;
        f4v t = k4 * q4;
        float p = t.x + t.y + t.z + t.w;
        p += __shfl_xor(p, 1);
        p += __shfl_xor(p, 2);
        p += __shfl_xor(p, 4);
        p += __shfl_xor(p, 8);
        p += __shfl_xor(p, 16);
        if (l32 == 0) sc[r] = p * SCALE;
    }
    // new-token score by wave 0 (from LDS q/k_new)
    if (tid < 64) {
        float pd = qkvs[2 * tid] * qkvs[D + 2 * tid]
                 + qkvs[2 * tid + 1] * qkvs[D + 2 * tid + 1];
        pd += __shfl_xor(pd, 1);
        pd += __shfl_xor(pd, 2);
        pd += __shfl_xor(pd, 4);
        pd += __shfl_xor(pd, 8);
        pd += __shfl_xor(pd, 16);
        pd += __shfl_xor(pd, 32);
        if (tid == 0) sc[S] = pd * SCALE;
    }
    __syncthreads();

    // ---- block softmax over sc[0..2048] ----
    const float s0v = sc[tid];
    const float s1v = sc[tid + 1024];
    const float sxv = (tid == 0) ? sc[S] : -1e30f;
    float m = fmaxf(fmaxf(s0v, s1v), sxv);
#pragma unroll
    for (int off = 1; off < 64; off <<= 1) m = fmaxf(m, __shfl_xor(m, off));
    if (lane == 0) swm[wave] = m;
    __syncthreads();
    float M = swm[0];
#pragma unroll
    for (int g = 1; g < 16; ++g) M = fmaxf(M, swm[g]);
    const float e0 = __expf(s0v - M);
    const float e1 = __expf(s1v - M);
    sc[tid] = e0;
    sc[tid + 1024] = e1;
    float lsum = e0 + e1;
    if (tid == 0) {
        const float e2 = __expf(sxv - M);
        sc[S] = e2;
        lsum += e2;
    }
#pragma unroll
    for (int off = 1; off < 64; off <<= 1) lsum += __shfl_xor(lsum, off);
    if (lane == 0) swl[wave] = lsum;
    __syncthreads();
    float L = swl[0];
#pragma unroll
    for (int g = 1; g < 16; ++g) L += swl[g];
    const float invL = 1.0f / L;

    // ---- V-pass: copy + weighted accumulate (1 carried FMA) ----
    f4v acc = (f4v){0.f, 0.f, 0.f, 0.f};
#pragma unroll 8
    for (int it = 0; it < S / 32; ++it) {
        const int r = it * 32 + rg;
        const size_t off = (size_t)r * 32 + l32;
        f4v v4 = __builtin_nontemporal_load(&vin[off]);
        vout[off] = v4;
        acc += v4 * sc[r];
    }

    // ---- combine 32 rowgroups + new token, normalize, write ----
    ((f4v*)sacc)[rg * 32 + l32] = acc;
    __syncthreads();

    if (tid < D) {
        float y = 0.f;
#pragma unroll
        for (int g = 0; g < 32; ++g) y += sacc[g * D + tid];
        y = fmaf(sc[S], qkvs[2 * D + tid], y);
        ys_g[(size_t)bh * D + tid] = y * invL;
    }
}

// ---------------------------------------------------------------------------
// Kernel 2: out-proj + bias + residual + LayerNorm.  One block per b,
// 1024 threads.  GEMV: thread t -> d = t>>3, j-chunk sub = t&7.
// ---------------------------------------------------------------------------
__global__ void __launch_bounds__(1024)
out_proj_kernel(const float* __restrict__ x,
                const float* __restrict__ ys_g,
                const float* __restrict__ Wout,
                const float* __restrict__ bout,
                float* __restrict__ out) {
    const int b = blockIdx.x;
    const int t = threadIdx.x;
    __shared__ float ys[DT];        // 8 KB
    __shared__ float pp[D * 8];     // 4 KB
    __shared__ float tb[D];

    ys[t]        = ys_g[(size_t)b * DT + t];
    ys[t + 1024] = ys_g[(size_t)b * DT + t + 1024];
    __syncthreads();

    {
        const int d = t >> 3;
        const int sub = t & 7;
        const float* w = Wout + (size_t)d * DT + sub * 256;
        const float* y = ys + sub * 256;
        float acc = 0.f;
#pragma unroll
        for (int j = 0; j < 256; j += 4) {
            float4 w4 = *reinterpret_cast<const float4*>(w + j);
            acc = fmaf(w4.x, y[j + 0], acc);
            acc = fmaf(w4.y, y[j + 1], acc);
            acc = fmaf(w4.z, y[j + 2], acc);
            acc = fmaf(w4.w, y[j + 3], acc);
        }
        pp[d * 8 + sub] = acc;
    }
    __syncthreads();

    float val = 0.f;
    if (t < D) {
        float a = 0.f;
#pragma unroll
        for (int g = 0; g < 8; ++g) a += pp[t * 8 + g];
        val = a + bout[t] + x[b * D + t];
        tb[t] = val;
    }
    __syncthreads();
    for (int off = 64; off > 0; off >>= 1) {
        if (t < off) tb[t] += tb[t + off];
        __syncthreads();
    }
    const float mu = tb[0] * (1.0f / D);
    __syncthreads();
    const float diff = val - mu;
    if (t < D) tb[t] = diff * diff;
    __syncthreads();
    for (int off = 64; off > 0; off >>= 1) {
        if (t < off) tb[t] += tb[t + off];
        __syncthreads();
    }
    const float var = tb[0] * (1.0f / D);
    if (t < D) out[(size_t)b * D + t] = diff / sqrtf(var + EPS);
}

// ---------------------------------------------------------------------------
extern "C" void kernel_launch(void* const* d_in, const int* in_sizes, int n_in,
                              void* d_out, int out_size, void* d_ws, size_t ws_size,
                              hipStream_t stream) {
    const float* x      = (const float*)d_in[0];
    const float* past_k = (const float*)d_in[1];
    const float* past_v = (const float*)d_in[2];
    const float* Wqkv   = (const float*)d_in[3];
    const float* bqkv   = (const float*)d_in[4];
    const float* Wout   = (const float*)d_in[5];
    const float* bout   = (const float*)d_in[6];

    float* out   = (float*)d_out;                       // (B,1,D)
    float* out_k = out + (size_t)B * D;                 // (B,H,S1,D)
    float* out_v = out_k + (size_t)B * H * S1 * D;      // (B,H,S1,D)

    float* ys_g = (float*)d_ws;                         // B*DT

    attn_kernel<<<B * H, 1024, 0, stream>>>(
        x, Wqkv, bqkv, past_k, past_v, out_k, out_v, ys_g);
    out_proj_kernel<<<B, 1024, 0, stream>>>(
        x, ys_g, Wout, bout, out);
}